// Round 8
// baseline (936.969 us; speedup 1.0000x reference)
//
#include <hip/hip_runtime.h>
#include <hip/hip_bf16.h>
#include <cstddef>
#include <cstdint>

// ---------------- problem constants ----------------
constexpr int B = 2, L = 2048, DIM = 2048;
constexpr int HK = 16, HV = 32, DK = 128, DV = 128;
constexpr int KEY_DIM = HK * DK;                    // 2048
constexpr int VAL_DIM = HV * DV;                    // 4096
constexpr int CONV_DIM = 2 * KEY_DIM + VAL_DIM;     // 8192
constexpr int NPROJ = CONV_DIM + VAL_DIM + HV + HV; // 12352
constexpr int NPAD  = ((NPROJ + 255) / 256) * 256;  // 12544 (128-tileable)
constexpr size_t ROWS = (size_t)B * L;              // 4096
constexpr float EPS = 1e-6f;
constexpr int CHUNK = 64, NCHUNK = L / CHUNK;       // 32 chunks
constexpr int NCH_TOT = B * HV * NCHUNK;            // 2048 chunk-head blocks
constexpr int CONV_LT = 16;                         // conv L-tiles
constexpr int CONV_TL = L / CONV_LT;                // 128

// workspace layout (BYTE offsets). Total ~188 MB (bf16 staging overlaid).
constexpr size_t OFF_QKV  = 0;                                   // bf16
constexpr size_t OFF_Z    = OFF_QKV + ROWS * CONV_DIM * 2;       // bf16 (y in-place)
constexpr size_t OFF_A    = OFF_Z   + ROWS * VAL_DIM * 2;        // f32
constexpr size_t OFF_B    = OFF_A   + ROWS * HV * 4;
constexpr size_t OFF_G    = OFF_B   + ROWS * HV * 4;             // g (log-space)
constexpr size_t OFF_BETA = OFF_G   + ROWS * HV * 4;
constexpr size_t OFF_U    = OFF_BETA + ROWS * HV * 4;            // f32 U = T(BV)
constexpr size_t OFF_WQK  = OFF_U + (size_t)NCH_TOT * CHUNK * DV * 4;  // bf16 Wqk
constexpr size_t OFF_HALO = OFF_WQK + (size_t)NCH_TOT * CHUNK * CHUNK * 2; // conv halos
constexpr size_t WS_NEED_BYTES = OFF_HALO + (size_t)3 * B * CONV_LT * CONV_DIM * 2;
// overlays (lifetime-disjoint):
constexpr size_t OFF_WCAT = OFF_U;    // Wcat bf16 (NPAD x DIM) until inproj done
constexpr size_t OFF_XB   = OFF_WQK;  // x bf16 until inproj done
constexpr size_t OFF_WOB  = OFF_U;    // Wout bf16 after chunk_scan2
static_assert((size_t)NPAD * DIM * 2 <= (size_t)NCH_TOT * CHUNK * DV * 4, "Wcat fits U");

// ---------------- bf16 helpers ----------------
__device__ __forceinline__ float bf2f(unsigned short u) {
    union { float f; uint32_t i; } c; c.i = ((uint32_t)u) << 16; return c.f;
}
__device__ __forceinline__ unsigned short f2bf(float f) {
    union { float f; uint32_t u; } c; c.f = f;
    uint32_t u = c.u + 0x7FFFu + ((c.u >> 16) & 1u);   // RTNE
    return (unsigned short)(u >> 16);
}
__device__ __forceinline__ uint32_t pk2(float a, float b) {
    return (uint32_t)f2bf(a) | ((uint32_t)f2bf(b) << 16);
}

// MFMA fragment types (16x16x32 bf16)
typedef __attribute__((ext_vector_type(8))) short bfrag;   // 8 bf16
typedef __attribute__((ext_vector_type(4))) float ffrag;   // 4 f32

// async global->LDS, 16B per lane (dest is wave-uniform base + lane*16)
__device__ __forceinline__ void gload16(const unsigned short* g, unsigned short* l) {
    __builtin_amdgcn_global_load_lds(
        (const __attribute__((address_space(1))) uint32_t*)g,
        (__attribute__((address_space(3))) uint32_t*)l, 16, 0, 0);
}

// ================= f32 -> bf16 conversion kernels =================
__device__ __forceinline__ const float* w_row_multi(int n, const float* Wq, const float* Wz,
                                                    const float* Wa, const float* Wb) {
    if (n < CONV_DIM)                return Wq + (size_t)n * DIM;
    if (n < CONV_DIM + VAL_DIM)      return Wz + (size_t)(n - CONV_DIM) * DIM;
    if (n < CONV_DIM + VAL_DIM + HV) return Wa + (size_t)(n - CONV_DIM - VAL_DIM) * DIM;
    return Wb + (size_t)(n - CONV_DIM - VAL_DIM - HV) * DIM;
}

__global__ __launch_bounds__(256) void cvt_wcat(
    const float* __restrict__ Wq, const float* __restrict__ Wz,
    const float* __restrict__ Wa, const float* __restrict__ Wb,
    unsigned short* __restrict__ dst)
{
    const int r = blockIdx.x;            // 0..NPAD-1
    const int c = threadIdx.x * 8;       // 256*8 = 2048 = DIM
    uint4 o;
    if (r < NPROJ) {
        const float* s = w_row_multi(r, Wq, Wz, Wa, Wb) + c;
        float4 v0 = *(const float4*)s;
        float4 v1 = *(const float4*)(s + 4);
        o = make_uint4(pk2(v0.x, v0.y), pk2(v0.z, v0.w), pk2(v1.x, v1.y), pk2(v1.z, v1.w));
    } else {
        o = make_uint4(0u, 0u, 0u, 0u);
    }
    *(uint4*)&dst[(size_t)r * DIM + c] = o;
}

__global__ __launch_bounds__(256) void cvt_f32bf(const float* __restrict__ src,
                                                 unsigned short* __restrict__ dst, int cols)
{
    const size_t r = blockIdx.x;
    for (int c = threadIdx.x * 8; c < cols; c += 256 * 8) {
        const float* s = src + r * cols + c;
        float4 v0 = *(const float4*)s;
        float4 v1 = *(const float4*)(s + 4);
        *(uint4*)&dst[r * cols + c] =
            make_uint4(pk2(v0.x, v0.y), pk2(v0.z, v0.w), pk2(v1.x, v1.y), pk2(v1.z, v1.w));
    }
}

// ================= shared GEMM epilogue helper (inproj) =================
__device__ __forceinline__ void store_multi(int m, int n, float v,
                                            unsigned short* qkv, unsigned short* z,
                                            float* a, float* b) {
    if (n < CONV_DIM) {
        qkv[(size_t)m * CONV_DIM + n] = f2bf(v);
    } else if (n < CONV_DIM + VAL_DIM) {
        z[(size_t)m * VAL_DIM + (n - CONV_DIM)] = f2bf(v);
    } else if (n < CONV_DIM + VAL_DIM + HV) {
        a[(size_t)m * HV + (n - CONV_DIM - VAL_DIM)] = v;
    } else if (n < NPROJ) {
        b[(size_t)m * HV + (n - CONV_DIM - VAL_DIM - HV)] = v;
    }
}

constexpr int BK = 64;

// ===================================================================
// 128x128-tile GEMM, 2-buffer counted-vmcnt pipeline, 64 KiB LDS
// -> 2 blocks/CU (cross-block waves fill barrier/vmcnt stalls, m97
// regime) + T4 (vmcnt(8), never 0 in steady state) + T5 setprio.
// 256 threads / 4 waves (2Mx2N), per-wave 64x64 out, 32 MFMA/K-tile.
// Schedule per iter kt: COMPUTE(kt) -> barrier -> STAGE(kt+2) ->
// vmcnt(8) -> barrier.  Race audit: WAR - STAGE(kt+2) writes
// buf[kt&1] after the barrier ending COMPUTE(kt) (all reads drained);
// RAW - vmcnt(8) confirms each wave's tile-(kt+1) loads landed, the
// following barrier makes it block-wide before COMPUTE(kt+1).
// ===================================================================
constexpr int GBUF2 = 16384;                 // ushorts per buffer (32 KiB)
constexpr int GEMM_SMEM = 2 * GBUF2 * 2;     // 65536 B

__global__ __launch_bounds__(256) void gemm_inproj_bf(
    const unsigned short* __restrict__ xb,     // (ROWS, DIM)
    const unsigned short* __restrict__ Wcat,   // (NPAD, DIM), pad rows zero
    unsigned short* __restrict__ qkv, unsigned short* __restrict__ z,
    float* __restrict__ a_out, float* __restrict__ b_out)
{
    extern __shared__ __align__(16) unsigned short lds[];

    constexpr int NT  = DIM / BK;              // 32 K-tiles
    constexpr int NBY = (int)ROWS / 128;       // 32
    constexpr int NBX = NPAD / 128;            // 98
    constexpr int NB  = NBY * NBX;             // 3136 (div by 8)
    const int id  = blockIdx.x;
    const int swz = (id & 7) * (NB >> 3) + (id >> 3);
    const int by  = swz & 31;                  // row tile
    const int bx  = swz >> 5;                  // col panel (L2 locality)
    const int row0 = by * 128;
    const int col0 = bx * 128;

    const int t = threadIdx.x, lane = t & 63, wid = t >> 6;
    const int wm = (wid >> 1) * 64, wn = (wid & 1) * 64;
    const int quad = lane >> 4, l16 = lane & 15;
    const int x7 = l16 & 7;

    ffrag acc[4][4];
#pragma unroll
    for (int i = 0; i < 4; ++i)
#pragma unroll
        for (int j = 0; j < 4; ++j) acc[i][j] = (ffrag)0.f;

    const int srow = t >> 3;                   // 0..31
    const int scol = (((t & 7) ^ (srow & 7)) * 8);   // pre-swizzled source slot
    const unsigned short* aS = xb   + (size_t)(row0 + srow) * DIM + scol;
    const unsigned short* bS = Wcat + (size_t)(col0 + srow) * DIM + scol;
    unsigned short* aD0 = lds + (wid * 8) * 64;           // wave-uniform dest
    unsigned short* bD0 = lds + 8192 + (wid * 8) * 64;

    auto STAGE = [&](int kt) {
        const int b = kt & 1;
        unsigned short* aD = aD0 + b * GBUF2;
        unsigned short* bD = bD0 + b * GBUF2;
        const int k0 = kt * BK;
#pragma unroll
        for (int g = 0; g < 4; ++g) {
            gload16(aS + (size_t)(g * 32) * DIM + k0, aD + g * 32 * 64);
            gload16(bS + (size_t)(g * 32) * DIM + k0, bD + g * 32 * 64);
        }
    };

    auto COMPUTE = [&](int kt) {
        const int b = kt & 1;
        const unsigned short* A  = lds + b * GBUF2;
        const unsigned short* Bm = lds + b * GBUF2 + 8192;
#pragma unroll
        for (int kk = 0; kk < 2; ++kk) {
            const int so = ((kk * 4 + quad) ^ x7) * 8;
            bfrag aF[4], bF[4];
#pragma unroll
            for (int m = 0; m < 4; ++m)
                aF[m] = *(const bfrag*)&A[(wm + m * 16 + l16) * 64 + so];
#pragma unroll
            for (int n = 0; n < 4; ++n)
                bF[n] = *(const bfrag*)&Bm[(wn + n * 16 + l16) * 64 + so];
            __builtin_amdgcn_s_setprio(1);
#pragma unroll
            for (int m = 0; m < 4; ++m)
#pragma unroll
                for (int n = 0; n < 4; ++n)
                    acc[m][n] = __builtin_amdgcn_mfma_f32_16x16x32_bf16(
                        aF[m], bF[n], acc[m][n], 0, 0, 0);
            __builtin_amdgcn_s_setprio(0);
        }
    };

    STAGE(0); STAGE(1);
    asm volatile("s_waitcnt vmcnt(8)" ::: "memory");   // tile 0 landed (own)
    asm volatile("s_barrier" ::: "memory");
    for (int kt = 0; kt < NT; ++kt) {
        COMPUTE(kt);
        if (kt == NT - 1) break;
        asm volatile("s_barrier" ::: "memory");        // reads of buf kt done
        if (kt + 2 < NT) {
            STAGE(kt + 2);                             // overwrites buf[kt&1]
            asm volatile("s_waitcnt vmcnt(8)" ::: "memory");  // tile kt+1 landed
        } else {
            asm volatile("s_waitcnt vmcnt(0)" ::: "memory");
        }
        asm volatile("s_barrier" ::: "memory");        // block-wide: kt+1 ready
    }

#pragma unroll
    for (int m = 0; m < 4; ++m)
#pragma unroll
        for (int n = 0; n < 4; ++n) {
            int gr = row0 + wm + m * 16 + quad * 4;
            int gc = col0 + wn + n * 16 + l16;
#pragma unroll
            for (int reg = 0; reg < 4; ++reg)
                store_multi(gr + reg, gc, acc[m][n][reg], qkv, z, a_out, b_out);
        }
}

__global__ __launch_bounds__(256) void gemm_outproj_bf(
    const unsigned short* __restrict__ A,    // (ROWS, VAL_DIM)
    const unsigned short* __restrict__ Wb,   // (DIM, VAL_DIM)
    float* __restrict__ C)                   // (ROWS, DIM)
{
    extern __shared__ __align__(16) unsigned short lds[];

    constexpr int NT  = VAL_DIM / BK;          // 64 K-tiles
    constexpr int NBY = (int)ROWS / 128;       // 32
    constexpr int NBX = DIM / 128;             // 16
    constexpr int NB  = NBY * NBX;             // 512 = one 2-block/CU round
    const int id  = blockIdx.x;
    const int swz = (id & 7) * (NB >> 3) + (id >> 3);
    const int by  = swz & 31;
    const int bx  = swz >> 5;
    const int row0 = by * 128;
    const int col0 = bx * 128;

    const int t = threadIdx.x, lane = t & 63, wid = t >> 6;
    const int wm = (wid >> 1) * 64, wn = (wid & 1) * 64;
    const int quad = lane >> 4, l16 = lane & 15;
    const int x7 = l16 & 7;

    ffrag acc[4][4];
#pragma unroll
    for (int i = 0; i < 4; ++i)
#pragma unroll
        for (int j = 0; j < 4; ++j) acc[i][j] = (ffrag)0.f;

    const int srow = t >> 3;
    const int scol = (((t & 7) ^ (srow & 7)) * 8);
    const unsigned short* aS = A  + (size_t)(row0 + srow) * VAL_DIM + scol;
    const unsigned short* bS = Wb + (size_t)(col0 + srow) * VAL_DIM + scol;
    unsigned short* aD0 = lds + (wid * 8) * 64;
    unsigned short* bD0 = lds + 8192 + (wid * 8) * 64;

    auto STAGE = [&](int kt) {
        const int b = kt & 1;
        unsigned short* aD = aD0 + b * GBUF2;
        unsigned short* bD = bD0 + b * GBUF2;
        const int k0 = kt * BK;
#pragma unroll
        for (int g = 0; g < 4; ++g) {
            gload16(aS + (size_t)(g * 32) * VAL_DIM + k0, aD + g * 32 * 64);
            gload16(bS + (size_t)(g * 32) * VAL_DIM + k0, bD + g * 32 * 64);
        }
    };

    auto COMPUTE = [&](int kt) {
        const int b = kt & 1;
        const unsigned short* Am = lds + b * GBUF2;
        const unsigned short* Bm = lds + b * GBUF2 + 8192;
#pragma unroll
        for (int kk = 0; kk < 2; ++kk) {
            const int so = ((kk * 4 + quad) ^ x7) * 8;
            bfrag aF[4], bF[4];
#pragma unroll
            for (int m = 0; m < 4; ++m)
                aF[m] = *(const bfrag*)&Am[(wm + m * 16 + l16) * 64 + so];
#pragma unroll
            for (int n = 0; n < 4; ++n)
                bF[n] = *(const bfrag*)&Bm[(wn + n * 16 + l16) * 64 + so];
            __builtin_amdgcn_s_setprio(1);
#pragma unroll
            for (int m = 0; m < 4; ++m)
#pragma unroll
                for (int n = 0; n < 4; ++n)
                    acc[m][n] = __builtin_amdgcn_mfma_f32_16x16x32_bf16(
                        aF[m], bF[n], acc[m][n], 0, 0, 0);
            __builtin_amdgcn_s_setprio(0);
        }
    };

    STAGE(0); STAGE(1);
    asm volatile("s_waitcnt vmcnt(8)" ::: "memory");
    asm volatile("s_barrier" ::: "memory");
    for (int kt = 0; kt < NT; ++kt) {
        COMPUTE(kt);
        if (kt == NT - 1) break;
        asm volatile("s_barrier" ::: "memory");
        if (kt + 2 < NT) {
            STAGE(kt + 2);
            asm volatile("s_waitcnt vmcnt(8)" ::: "memory");
        } else {
            asm volatile("s_waitcnt vmcnt(0)" ::: "memory");
        }
        asm volatile("s_barrier" ::: "memory");
    }

#pragma unroll
    for (int m = 0; m < 4; ++m)
#pragma unroll
        for (int n = 0; n < 4; ++n) {
            int gr = row0 + wm + m * 16 + quad * 4;
            int gc = col0 + wn + n * 16 + l16;
#pragma unroll
            for (int reg = 0; reg < 4; ++reg)
                C[(size_t)(gr + reg) * DIM + gc] = acc[m][n][reg];
        }
}

// ================= conv halo snapshot (race-free tiling) =================
__global__ __launch_bounds__(256) void conv_halo(const unsigned short* __restrict__ qkv,
                                                 unsigned short* __restrict__ hbuf)
{
    int idx = blockIdx.x * 256 + threadIdx.x;     // B * CONV_LT * CONV_DIM
    int c    = idx & (CONV_DIM - 1);
    int tile = (idx >> 13) & (CONV_LT - 1);
    int b    = idx >> 17;
    int l0 = tile * CONV_TL;
    const unsigned short* p = qkv + (size_t)b * L * CONV_DIM + c;
#pragma unroll
    for (int j = 0; j < 3; ++j) {
        unsigned short v = (tile > 0) ? p[(size_t)(l0 - 3 + j) * CONV_DIM] : (unsigned short)0;
        hbuf[((size_t)j * B * CONV_LT + b * CONV_LT + tile) * CONV_DIM + c] = v;
    }
}

// ================= depthwise causal conv1d + SiLU (L-tiled) =================
__global__ __launch_bounds__(256) void conv_silu(unsigned short* __restrict__ qkv,
                                                 const float* __restrict__ conv_w,
                                                 const unsigned short* __restrict__ hbuf)
{
    int idx = blockIdx.x * 256 + threadIdx.x;     // B * CONV_LT * CONV_DIM
    int c    = idx & (CONV_DIM - 1);
    int tile = (idx >> 13) & (CONV_LT - 1);
    int b    = idx >> 17;
    const float w0 = conv_w[c * 4 + 0];
    const float w1 = conv_w[c * 4 + 1];
    const float w2 = conv_w[c * 4 + 2];
    const float w3 = conv_w[c * 4 + 3];
    unsigned short* p = qkv + ((size_t)b * L + tile * CONV_TL) * CONV_DIM + c;
    const size_t hb = (size_t)b * CONV_LT + tile;
    float x0 = bf2f(hbuf[((size_t)0 * B * CONV_LT + hb) * CONV_DIM + c]);
    float x1 = bf2f(hbuf[((size_t)1 * B * CONV_LT + hb) * CONV_DIM + c]);
    float x2 = bf2f(hbuf[((size_t)2 * B * CONV_LT + hb) * CONV_DIM + c]);
    for (int l0 = 0; l0 < CONV_TL; l0 += 8) {
        float xv[8];
#pragma unroll
        for (int j = 0; j < 8; ++j) xv[j] = bf2f(p[(size_t)(l0 + j) * CONV_DIM]);
#pragma unroll
        for (int j = 0; j < 8; ++j) {
            float h = w0 * x0 + w1 * x1 + w2 * x2 + w3 * xv[j];
            float s = h / (1.f + __expf(-h));
            p[(size_t)(l0 + j) * CONV_DIM] = f2bf(s);
            x0 = x1; x1 = x2; x2 = xv[j];
        }
    }
}

// ================= l2norm of q,k heads =================
__global__ __launch_bounds__(256) void normqk(unsigned short* __restrict__ qkv)
{
    int wid  = blockIdx.x * 4 + (threadIdx.x >> 6);
    int lane = threadIdx.x & 63;
    int hk  = wid & 15;
    int sel = (wid >> 4) & 1;
    int row = wid >> 5;
    unsigned short* p = qkv + (size_t)row * CONV_DIM + sel * KEY_DIM + hk * DK;
    float x0 = bf2f(p[lane]), x1 = bf2f(p[lane + 64]);
    float ss = x0 * x0 + x1 * x1;
#pragma unroll
    for (int o = 32; o >= 1; o >>= 1) ss += __shfl_xor(ss, o);
    float sc = rsqrtf(ss + 1e-6f);
    if (sel == 0) sc *= 0.08838834764831845f;   // DK^-0.5
    p[lane]      = f2bf(x0 * sc);
    p[lane + 64] = f2bf(x1 * sc);
}

// ================= gate coefficients: g (log) and beta =================
__global__ __launch_bounds__(256) void gatecoef(const float* __restrict__ a_buf,
                                                const float* __restrict__ b_buf,
                                                const float* __restrict__ A_log,
                                                const float* __restrict__ dt_bias,
                                                float* __restrict__ glog,
                                                float* __restrict__ beta)
{
    int idx = blockIdx.x * blockDim.x + threadIdx.x;
    int h = idx & (HV - 1);
    float av = a_buf[idx];
    float bv = b_buf[idx];
    float x  = av + dt_bias[h];
    float sp = (x > 20.f) ? x : log1pf(__expf(x));
    glog[idx] = -__expf(A_log[h]) * sp;
    beta[idx] = 1.f / (1.f + __expf(-bv));
}

// ===================================================================
// Two-pass chunked gated delta rule (unchanged from round 7).
// ===================================================================

// shared strides
constexpr int RSK  = 136;   // 128-wide bf16 rows (128 data + 8 pad)
constexpr int RST  = 72;    // 64-wide bf16 rows (64 data + 8 pad)
constexpr int RSTD = 68;    // pass-1 X^T rows (64 data + 4 pad)
constexpr int RSR1 = 260;   // pass-1 RHS f32 rows (256 data + 4 pad)

// ---- pass-1 LDS layout ----
constexpr int P1_oKs  = 0;                       // 64*136*2 = 17408
constexpr int P1_oQs  = P1_oKs + 64 * RSK * 2;   // 17408
constexpr int P1_oDT  = 0;                       // overlay Ks+Qs: 256*68*2 = 34816
constexpr int P1_oAf  = P1_oQs + 64 * RSK * 2;   // 34816 (64*72*2 = 9216)
constexpr int P1_oRHS = P1_oAf + 64 * RST * 2;   // 44032 (64*260*4 = 66560)
constexpr int P1_oG   = P1_oRHS + 64 * RSR1 * 4; // 110592
constexpr int P1_oEG  = P1_oG + 256;
constexpr int P1_oBs  = P1_oEG + 256;
constexpr int P1_SMEM = P1_oBs + 256;            // 111616

__global__ __launch_bounds__(256, 1) void chunk_prep(
    unsigned short* __restrict__ qkv,     // v-slot overwritten with Wkn
    const float* __restrict__ glog,
    const float* __restrict__ beta,
    float* __restrict__ Ubuf,
    unsigned short* __restrict__ Wqkbuf)
{
    extern __shared__ __align__(16) char smem[];
    unsigned short* sKs = (unsigned short*)(smem + P1_oKs);
    unsigned short* sQs = (unsigned short*)(smem + P1_oQs);
    unsigned short* sDT = (unsigned short*)(smem + P1_oDT);
    unsigned short* sAf = (unsigned short*)(smem + P1_oAf);
    float* sRHS = (float*)(smem + P1_oRHS);
    float* sG   = (float*)(smem + P1_oG);
    float* sEG  = (float*)(smem + P1_oEG);
    float* sBs  = (float*)(smem + P1_oBs);

    const int bid = blockIdx.x;
    const int ch = bid & (NCHUNK - 1);
    const int h  = (bid >> 5) & (HV - 1);
    const int bb = bid >> 10;
    const int hk = h >> 1;
    const int t    = threadIdx.x;
    const int w    = t >> 6;
    const int lane = t & 63;
    const int quad = lane >> 4;
    const int l16  = lane & 15;
    const int quad8 = quad * 8;
    const size_t bL = (size_t)bb * L;
    const int l0 = ch * CHUNK;
    const int VOFF = 2 * KEY_DIM + h * DV;

    // ---- loads ----
    {
        const int r  = t >> 2;
        const int c0 = (t & 3) * 32;
        const unsigned short* grow = qkv + (bL + l0 + r) * CONV_DIM;
        const unsigned short* gq = grow + hk * DK + c0;
        const unsigned short* gk = grow + KEY_DIM + hk * DK + c0;
#pragma unroll
        for (int u = 0; u < 4; ++u) {
            *(uint4*)&sKs[r * RSK + c0 + 8 * u] = *(const uint4*)(gk + 8 * u);
            *(uint4*)&sQs[r * RSK + c0 + 8 * u] = *(const uint4*)(gq + 8 * u);
        }
        if (t < 64) {
            float gl = glog[(bL + l0 + t) * HV + h];
#pragma unroll
            for (int off = 1; off < 64; off <<= 1) {
                float v = __shfl_up(gl, off, 64);
                if (lane >= off) gl += v;
            }
            sG[t]  = gl;
            sEG[t] = __expf(gl);
            sBs[t] = beta[(bL + l0 + t) * HV + h];
        }
    }
    __syncthreads();

    // ---- A = K K^T, Wqk = Q K^T (wave w: cols j in [16w,16w+16)) ----
    {
        ffrag accA[4], accW[4];
#pragma unroll
        for (int mt = 0; mt < 4; ++mt) { accA[mt] = (ffrag)0.f; accW[mt] = (ffrag)0.f; }
#pragma unroll
        for (int kk = 0; kk < 4; ++kk) {
            bfrag bf = *(const bfrag*)&sKs[(16 * w + l16) * RSK + 32 * kk + quad8];
#pragma unroll
            for (int mt = 0; mt < 4; ++mt) {
                bfrag ak = *(const bfrag*)&sKs[(16 * mt + l16) * RSK + 32 * kk + quad8];
                bfrag aq = *(const bfrag*)&sQs[(16 * mt + l16) * RSK + 32 * kk + quad8];
                accA[mt] = __builtin_amdgcn_mfma_f32_16x16x32_bf16(ak, bf, accA[mt], 0, 0, 0);
                accW[mt] = __builtin_amdgcn_mfma_f32_16x16x32_bf16(aq, bf, accW[mt], 0, 0, 0);
            }
        }
        const int j = 16 * w + l16;
        const float gj = sG[j];
        unsigned short* Wqp = Wqkbuf + (size_t)bid * (CHUNK * CHUNK);
#pragma unroll
        for (int mt = 0; mt < 4; ++mt)
#pragma unroll
            for (int reg = 0; reg < 4; ++reg) {
                int i = 16 * mt + quad * 4 + reg;
                float sc = __expf(sG[i] - gj);
                sAf[i * RST + j] = f2bf((j < i) ? sBs[i] * sc * accA[mt][reg] : 0.f);
                Wqp[i * CHUNK + j] = f2bf((j <= i) ? sc * accW[mt][reg] : 0.f);
            }
    }

    // ---- RHS = [ B*V | B*eG*K ] (f32) ----
    {
        const int r  = t >> 2;
        const int c0 = (t & 3) * 32;
        const float be  = sBs[r];
        const float beg = be * sEG[r];
        const unsigned short* gv = qkv + (bL + l0 + r) * CONV_DIM + VOFF + c0;
#pragma unroll
        for (int u = 0; u < 4; ++u) {
            uint4 vv = *(const uint4*)(gv + 8 * u);
            const unsigned short* vp = (const unsigned short*)&vv;
#pragma unroll
            for (int e = 0; e < 8; ++e)
                sRHS[r * RSR1 + c0 + 8 * u + e] = be * bf2f(vp[e]);
        }
#pragma unroll
        for (int u = 0; u < 4; ++u)
#pragma unroll
            for (int e = 0; e < 8; ++e)
                sRHS[r * RSR1 + 128 + c0 + 8 * u + e] =
                    beg * bf2f(sKs[r * RSK + c0 + 8 * u + e]);
    }
    __syncthreads();   // Ks/Qs reads done -> DT overlay writable

    // zero X^T staging (padding rows read by block-solve MFMAs)
    for (int u = t; u < 256 * RSTD / 2; u += 256) ((uint32_t*)sDT)[u] = 0;

    // ---- blocked forward substitution, 256 columns ----
    float* Up = Ubuf + (size_t)bid * (CHUNK * DV);
    for (int sb = 0; sb < 4; ++sb) {
        const int sb16 = 16 * sb;
        if (sb > 0) {
            const int kbn = (sb + 1) >> 1;
            ffrag c16[4];
#pragma unroll
            for (int nt = 0; nt < 4; ++nt) c16[nt] = (ffrag)0.f;
            for (int kb = 0; kb < kbn; ++kb) {
                bfrag af = *(const bfrag*)&sAf[(sb16 + l16) * RST + 32 * kb + quad8];
#pragma unroll
                for (int nt = 0; nt < 4; ++nt) {
                    bfrag bf = *(const bfrag*)&sDT[(64 * w + 16 * nt + l16) * RSTD + 32 * kb + quad8];
                    c16[nt] = __builtin_amdgcn_mfma_f32_16x16x32_bf16(af, bf, c16[nt], 0, 0, 0);
                }
            }
#pragma unroll
            for (int nt = 0; nt < 4; ++nt)
#pragma unroll
                for (int reg = 0; reg < 4; ++reg)
                    sRHS[(sb16 + quad * 4 + reg) * RSR1 + 64 * w + 16 * nt + l16] -= c16[nt][reg];
        }
        __syncthreads();
        {   // serial 16x16 unit-lower solve; thread t owns column t
            const int c = t;
            float d16[16];
#pragma unroll
            for (int e = 0; e < 16; ++e) {
                const int i = sb16 + e;
                float acc = sRHS[i * RSR1 + c];
#pragma unroll
                for (int f = 0; f < 16; ++f)
                    if (f < e) acc -= bf2f(sAf[i * RST + sb16 + f]) * d16[f];
                d16[e] = acc;
            }
#pragma unroll
            for (int e = 0; e < 16; e += 2)
                *(uint32_t*)&sDT[c * RSTD + sb16 + e] = pk2(d16[e], d16[e + 1]);
            if (c < 128) {
                float* up = Up + c;
#pragma unroll
                for (int e = 0; e < 16; ++e) up[(size_t)(sb16 + e) * DV] = d16[e];
            } else {
                unsigned short* wp = qkv + (bL + l0 + sb16) * CONV_DIM + VOFF + (c - 128);
#pragma unroll
                for (int e = 0; e < 16; ++e) wp[(size_t)e * CONV_DIM] = f2bf(-d16[e]);
            }
        }
        __syncthreads();
    }
}

// ---- pass-2 LDS layout (8-wave version) ----
constexpr int P2_oSTb = 0;                         // 128*136*2 = 34816
constexpr int P2_oWk  = P2_oSTb + 128 * RSK * 2;   // +17408
constexpr int P2_oQs  = P2_oWk + 64 * RSK * 2;     // +17408
constexpr int P2_oKT  = P2_oQs + 64 * RSK * 2;     // +18432
constexpr int P2_oWqk = P2_oKT + 128 * RST * 2;    // +9216
constexpr int P2_oDT  = P2_oWqk + 64 * RST * 2;    // +18432
constexpr int P2_oDdT = P2_oDT + 128 * RST * 2;    // +18432
constexpr int P2_oEG  = P2_oDdT + 128 * RST * 2;   // 134144
constexpr int P2_oEGd = P2_oEG + 256;              // 134400
constexpr int P2_oNW  = P2_oEGd + 256;             // 134656
constexpr int P2_oP   = P2_oNW + 512;              // 135168 (wave-pair RMS partials)
constexpr int P2_SMEM = P2_oP + 512;               // 135680

// 512 threads / 8 waves: 2 waves/SIMD for latency hiding; per-wave MFMA halves.
__global__ __launch_bounds__(512, 1) void chunk_scan2(
    const unsigned short* __restrict__ qkv,   // q,k raw; v-slot holds Wkn
    const float* __restrict__ glog,
    const float* __restrict__ Ubuf,
    const unsigned short* __restrict__ Wqkbuf,
    unsigned short* __restrict__ z_io,
    const float* __restrict__ norm_w)
{
    extern __shared__ __align__(16) char smem[];
    unsigned short* sSTb = (unsigned short*)(smem + P2_oSTb);
    unsigned short* sWk  = (unsigned short*)(smem + P2_oWk);
    unsigned short* sQs  = (unsigned short*)(smem + P2_oQs);
    unsigned short* sKT  = (unsigned short*)(smem + P2_oKT);
    unsigned short* sWqk = (unsigned short*)(smem + P2_oWqk);
    unsigned short* sDT  = (unsigned short*)(smem + P2_oDT);
    unsigned short* sDdT = (unsigned short*)(smem + P2_oDdT);
    float* sEG  = (float*)(smem + P2_oEG);
    float* sEGd = (float*)(smem + P2_oEGd);
    float* sNW  = (float*)(smem + P2_oNW);
    float* sP   = (float*)(smem + P2_oP);

    const int bb = blockIdx.x >> 5;
    const int h  = blockIdx.x & (HV - 1);
    const int hk = h >> 1;
    const int t    = threadIdx.x;            // 0..511
    const int w    = t >> 6;                 // 0..7
    const int lane = t & 63;
    const int quad = lane >> 4;
    const int l16  = lane & 15;
    const int quad8 = quad * 8;
    const int rg = w >> 1;                   // O-phase row group
    const int dh = w & 1;                    // O-phase dv half
    const size_t bL = (size_t)bb * L;
    const int VOFF = 2 * KEY_DIM + h * DV;
    const size_t chbase0 = ((size_t)bb * HV + h) * NCHUNK;

    const int r  = t >> 3;        // staging row 0..63
    const int c0 = (t & 7) * 16;  // staging col
    const int cw = (t & 7) * 8;   // Wqk col

    // persistent state: ST[dv][dk], wave w owns dv in [16w,16w+16)
    ffrag accS[8];
#pragma unroll
    for (int nt = 0; nt < 8; ++nt) accS[nt] = (ffrag)0.f;

    for (int u = t; u < 64 * RSK; u += 512) ((uint32_t*)sSTb)[u] = 0;  // 128*136 bf16
    if (t < 128) sNW[t] = norm_w[t];

    // prefetch registers (issue-early / write-late)
    uint4 pQ[2], pK[2], pWk[2], pWqk;
    float pGl;

    auto PF = [&](int ch) {
        const int l0p = ch * CHUNK;
        const unsigned short* grow = qkv + (bL + l0p + r) * CONV_DIM;
        const unsigned short* gq = grow + hk * DK + c0;
        const unsigned short* gk = grow + KEY_DIM + hk * DK + c0;
        const unsigned short* gw = grow + VOFF + c0;
#pragma unroll
        for (int u = 0; u < 2; ++u) {
            pQ[u]  = *(const uint4*)(gq + 8 * u);
            pK[u]  = *(const uint4*)(gk + 8 * u);
            pWk[u] = *(const uint4*)(gw + 8 * u);
        }
        pWqk = *(const uint4*)(Wqkbuf + (chbase0 + ch) * (CHUNK * CHUNK) + r * CHUNK + cw);
        pGl = glog[(bL + l0p + (t & 63)) * HV + h];
    };

    PF(0);

    for (int ch = 0; ch < NCHUNK; ++ch) {
        const int l0 = ch * CHUNK;
        const size_t cb = chbase0 + ch;
        __syncthreads();   // A: prev STb written; all prev-phase LDS reads done

        // ---- U -> accD direct from global ----
        ffrag accD[4];
        {
            const float* up = Ubuf + cb * (CHUNK * DV) + (size_t)(quad * 4) * DV + 16 * w + l16;
#pragma unroll
            for (int mt = 0; mt < 4; ++mt)
#pragma unroll
                for (int reg = 0; reg < 4; ++reg)
                    accD[mt][reg] = up[(size_t)(16 * mt + reg) * DV];
        }
        // ---- z gate prefetch (consumed in epilogue; wave-pair layout) ----
        unsigned short pz[4][4];
        {
            const unsigned short* zp =
                z_io + (bL + l0 + 16 * rg + quad * 4) * (size_t)VAL_DIM + h * DV + 64 * dh + l16;
#pragma unroll
            for (int nt = 0; nt < 4; ++nt)
#pragma unroll
                for (int reg = 0; reg < 4; ++reg)
                    pz[nt][reg] = zp[(size_t)reg * VAL_DIM + 16 * nt];
        }

        // ---- stage LDS from prefetch regs ----
#pragma unroll
        for (int u = 0; u < 2; ++u) {
            *(uint4*)&sQs[r * RSK + c0 + 8 * u] = pQ[u];
            *(uint4*)&sWk[r * RSK + c0 + 8 * u] = pWk[u];
            const unsigned short* kp = (const unsigned short*)&pK[u];
#pragma unroll
            for (int e = 0; e < 8; ++e) {
                const int c = c0 + 8 * u + e;
                sKT[c * RST + ((((r >> 3) ^ (c >> 3)) & 7) << 3) + (r & 7)] = kp[e];
            }
        }
        *(uint4*)&sWqk[r * RST + cw] = pWqk;

        // gates (cumulative log-decay scan, wave 0 only)
        {
            float gl = pGl;
            if (t < 64) {
#pragma unroll
                for (int off = 1; off < 64; off <<= 1) {
                    float v = __shfl_up(gl, off, 64);
                    if (lane >= off) gl += v;
                }
                float gc = __shfl(gl, 63, 64);
                sEG[t]  = __expf(gl);
                sEGd[t] = __expf(gc - gl);
            }
        }

        if (ch + 1 < NCHUNK) PF(ch + 1);   // next-chunk loads fly across compute
        __syncthreads();   // B

        // ---- Delta = U + Wkn . ST (wave w: dv = 16w + l16) ----
#pragma unroll
        for (int kk = 0; kk < 4; ++kk) {
            bfrag b0 = *(const bfrag*)&sSTb[(16 * w + l16) * RSK + 32 * kk + quad8];
#pragma unroll
            for (int mt = 0; mt < 4; ++mt) {
                bfrag af = *(const bfrag*)&sWk[(16 * mt + l16) * RSK + 32 * kk + quad8];
                accD[mt] = __builtin_amdgcn_mfma_f32_16x16x32_bf16(af, b0, accD[mt], 0, 0, 0);
            }
        }

        // ---- packed Delta^T / decayed Delta^T writes ----
        {
            const int dv = 16 * w + l16;
#pragma unroll
            for (int mt = 0; mt < 4; ++mt) {
                const int i0 = 16 * mt + quad * 4;
                const float e0 = sEGd[i0], e1 = sEGd[i0 + 1], e2 = sEGd[i0 + 2], e3 = sEGd[i0 + 3];
                const float d0 = accD[mt][0], d1 = accD[mt][1];
                const float d2 = accD[mt][2], d3 = accD[mt][3];
                *(uint32_t*)&sDT[dv * RST + i0]      = pk2(d0, d1);
                *(uint32_t*)&sDT[dv * RST + i0 + 2]  = pk2(d2, d3);
                *(uint32_t*)&sDdT[dv * RST + i0]     = pk2(d0 * e0, d1 * e1);
                *(uint32_t*)&sDdT[dv * RST + i0 + 2] = pk2(d2 * e2, d3 * e3);
            }
        }
        __syncthreads();   // D

        // ---- O = eG*(Q ST) + Wqk . Delta (wave pair: rows 16rg, dv half dh) ----
        ffrag accO[4];
#pragma unroll
        for (int nt = 0; nt < 4; ++nt) accO[nt] = (ffrag)0.f;
#pragma unroll
        for (int kk = 0; kk < 4; ++kk) {
            bfrag af = *(const bfrag*)&sQs[(16 * rg + l16) * RSK + 32 * kk + quad8];
#pragma unroll
            for (int nt = 0; nt < 4; ++nt) {
                bfrag bf = *(const bfrag*)&sSTb[(64 * dh + 16 * nt + l16) * RSK + 32 * kk + quad8];
                accO[nt] = __builtin_amdgcn_mfma_f32_16x16x32_bf16(af, bf, accO[nt], 0, 0, 0);
            }
        }
#pragma unroll
        for (int nt = 0; nt < 4; ++nt)
#pragma unroll
            for (int reg = 0; reg < 4; ++reg)
                accO[nt][reg] *= sEG[16 * rg + quad * 4 + reg];
#pragma unroll
        for (int kk = 0; kk < 2; ++kk) {
            bfrag af = *(const bfrag*)&sWqk[(16 * rg + l16) * RST + 32 * kk + quad8];
#pragma unroll
            for (int nt = 0; nt < 4; ++nt) {
                bfrag bf = *(const bfrag*)&sDT[(64 * dh + 16 * nt + l16) * RST + 32 * kk + quad8];
                accO[nt] = __builtin_amdgcn_mfma_f32_16x16x32_bf16(af, bf, accO[nt], 0, 0, 0);
            }
        }

        // RMSNorm partials for this dv-half (combine with partner wave after E)
        float p4[4];
#pragma unroll
        for (int reg = 0; reg < 4; ++reg) {
            float p = 0.f;
#pragma unroll
            for (int nt = 0; nt < 4; ++nt) p += accO[nt][reg] * accO[nt][reg];
#pragma unroll
            for (int m = 1; m < 16; m <<= 1) p += __shfl_xor(p, m, 64);
            p4[reg] = p;
        }
        if (l16 == 0) {
#pragma unroll
            for (int reg = 0; reg < 4; ++reg) sP[w * 16 + quad * 4 + reg] = p4[reg];
        }

        // ---- state update: ST = eGc*ST + DdT . KT (own dv rows; within-wave) ----
        {
            const float eGc = sEG[63];
#pragma unroll
            for (int nt = 0; nt < 8; ++nt)
#pragma unroll
                for (int reg = 0; reg < 4; ++reg) accS[nt][reg] *= eGc;
#pragma unroll
            for (int kk = 0; kk < 2; ++kk) {
                bfrag a0 = *(const bfrag*)&sDdT[(16 * w + l16) * RST + 32 * kk + quad8];
#pragma unroll
                for (int nt = 0; nt < 8; ++nt) {
                    const int ck = 16 * nt + l16;
                    bfrag bk = *(const bfrag*)&sKT[ck * RST +
                                 ((((4 * kk + quad) ^ (ck >> 3)) & 7) << 3)];
                    accS[nt] = __builtin_amdgcn_mfma_f32_16x16x32_bf16(a0, bk, accS[nt], 0, 0, 0);
                }
            }
        }
        __syncthreads();   // E: all STb/DT/DdT/KT reads done; sP written

        // ---- epilogue: combine pair partials, gated RMSNorm, write y over z ----
        {
            float inv[4];
#pragma unroll
            for (int reg = 0; reg < 4; ++reg) {
                float pp = p4[reg] + sP[(w ^ 1) * 16 + quad * 4 + reg];
                inv[reg] = rsqrtf(pp * (1.f / 128.f) + EPS);
            }
            unsigned short* zw =
                z_io + (bL + l0 + 16 * rg + quad * 4) * (size_t)VAL_DIM + h * DV + 64 * dh + l16;
#pragma unroll
            for (int nt = 0; nt < 4; ++nt) {
                const float nwv = sNW[64 * dh + 16 * nt + l16];
#pragma unroll
                for (int reg = 0; reg < 4; ++reg) {
                    float zv = bf2f(pz[nt][reg]);
                    float y = accO[nt][reg] * inv[reg] * nwv * (zv / (1.f + __expf(-zv)));
                    zw[(size_t)reg * VAL_DIM + 16 * nt] = f2bf(y);
                }
            }
        }

        // ---- materialize STb (bf16) for next chunk (own dv rows) ----
#pragma unroll
        for (int nt = 0; nt < 8; ++nt)
#pragma unroll
            for (int reg = 0; reg < 4; ++reg)
                sSTb[(16 * w + quad * 4 + reg) * RSK + 16 * nt + l16] = f2bf(accS[nt][reg]);
    }
}

// ---------------- launch ----------------
extern "C" void kernel_launch(void* const* d_in, const int* in_sizes, int n_in,
                              void* d_out, int out_size, void* d_ws, size_t ws_size,
                              hipStream_t stream)
{
    const float* x        = (const float*)d_in[0];
    const float* W_qkv    = (const float*)d_in[1];
    const float* W_z      = (const float*)d_in[2];
    const float* W_a      = (const float*)d_in[3];
    const float* W_b      = (const float*)d_in[4];
    const float* conv_w   = (const float*)d_in[5];
    const float* A_log    = (const float*)d_in[6];
    const float* dt_bias  = (const float*)d_in[7];
    const float* norm_w   = (const float*)d_in[8];
    const float* W_out    = (const float*)d_in[9];
    float* out = (float*)d_out;
    char*  ws  = (char*)d_ws;

    if (ws_size < WS_NEED_BYTES) return;

    unsigned short* qkv = (unsigned short*)(ws + OFF_QKV);
    unsigned short* z   = (unsigned short*)(ws + OFF_Z);
    float* a    = (float*)(ws + OFF_A);
    float* bbuf = (float*)(ws + OFF_B);
    float* gl   = (float*)(ws + OFF_G);
    float* beta = (float*)(ws + OFF_BETA);
    float* Ubuf = (float*)(ws + OFF_U);
    unsigned short* Wqkbuf = (unsigned short*)(ws + OFF_WQK);
    unsigned short* hbuf   = (unsigned short*)(ws + OFF_HALO);
    unsigned short* Wcat   = (unsigned short*)(ws + OFF_WCAT);  // overlay on U
    unsigned short* xb     = (unsigned short*)(ws + OFF_XB);    // overlay on Wqk
    unsigned short* Wob    = (unsigned short*)(ws + OFF_WOB);   // overlay on U

    static bool attr_set = false;
    if (!attr_set) {
        (void)hipFuncSetAttribute((const void*)chunk_prep,
                                  hipFuncAttributeMaxDynamicSharedMemorySize, P1_SMEM);
        (void)hipFuncSetAttribute((const void*)chunk_scan2,
                                  hipFuncAttributeMaxDynamicSharedMemorySize, P2_SMEM);
        (void)hipFuncSetAttribute((const void*)gemm_inproj_bf,
                                  hipFuncAttributeMaxDynamicSharedMemorySize, GEMM_SMEM);
        (void)hipFuncSetAttribute((const void*)gemm_outproj_bf,
                                  hipFuncAttributeMaxDynamicSharedMemorySize, GEMM_SMEM);
        attr_set = true;
    }

    // 0. pre-convert operands to bf16 (Wcat overlays U-region, xb overlays Wqk-region)
    cvt_wcat<<<NPAD, 256, 0, stream>>>(W_qkv, W_z, W_a, W_b, Wcat);
    cvt_f32bf<<<(int)ROWS, 256, 0, stream>>>(x, xb, DIM);
    // 1. fused input projections (128^2 tile, 2-buf counted-vmcnt, 2 blocks/CU)
    gemm_inproj_bf<<<((int)ROWS / 128) * (NPAD / 128), 256, GEMM_SMEM, stream>>>(
        xb, Wcat, qkv, z, a, bbuf);
    // 2. depthwise causal conv + silu (L-tiled, halo snapshot first)
    conv_halo<<<(B * CONV_LT * CONV_DIM) / 256, 256, 0, stream>>>(qkv, hbuf);
    conv_silu<<<(B * CONV_LT * CONV_DIM) / 256, 256, 0, stream>>>(qkv, conv_w, hbuf);
    // 3. l2norm q,k heads
    normqk<<<(B * L * 2 * HK) / 4, 256, 0, stream>>>(qkv);
    // 4. gate coefficients (log-space g)
    gatecoef<<<(B * L * HV) / 256, 256, 0, stream>>>(a, bbuf, A_log, dt_bias, gl, beta);
    // 5a. parallel chunk prep: A, Wqk, solve -> U (f32, overwrites Wcat), Wkn (v-slot)
    chunk_prep<<<NCH_TOT, 256, P1_SMEM, stream>>>(qkv, gl, beta, Ubuf, Wqkbuf);
    // 5b. sequential scan (8 waves, pipelined): Delta/O/state + fused gated RMSNorm
    chunk_scan2<<<B * HV, 512, P2_SMEM, stream>>>(qkv, gl, Ubuf, Wqkbuf, z, norm_w);
    // 5c. convert W_out to bf16 (U dead now; overlay)
    cvt_f32bf<<<DIM, 256, 0, stream>>>(W_out, Wob, VAL_DIM);
    // 6. output projection (128^2 tile, same pipeline; 512 blocks = 1 round)
    gemm_outproj_bf<<<((int)ROWS / 128) * (DIM / 128), 256, GEMM_SMEM, stream>>>(z, Wob, out);
}

// Round 9
// 880.813 us; speedup vs baseline: 1.0638x; 1.0638x over previous
//
#include <hip/hip_runtime.h>
#include <hip/hip_bf16.h>
#include <cstddef>
#include <cstdint>

// ---------------- problem constants ----------------
constexpr int B = 2, L = 2048, DIM = 2048;
constexpr int HK = 16, HV = 32, DK = 128, DV = 128;
constexpr int KEY_DIM = HK * DK;                    // 2048
constexpr int VAL_DIM = HV * DV;                    // 4096
constexpr int CONV_DIM = 2 * KEY_DIM + VAL_DIM;     // 8192
constexpr int NPROJ = CONV_DIM + VAL_DIM + HV + HV; // 12352
constexpr int NPAD  = ((NPROJ + 255) / 256) * 256;  // 12544
constexpr size_t ROWS = (size_t)B * L;              // 4096
constexpr float EPS = 1e-6f;
constexpr int CHUNK = 64, NCHUNK = L / CHUNK;       // 32 chunks
constexpr int NCH_TOT = B * HV * NCHUNK;            // 2048 chunk-head blocks
constexpr int CONV_LT = 8;                          // conv L-tiles
constexpr int CONV_TL = L / CONV_LT;                // 256

// workspace layout (BYTE offsets). Total ~188 MB (bf16 staging overlaid).
constexpr size_t OFF_QKV  = 0;                                   // bf16
constexpr size_t OFF_Z    = OFF_QKV + ROWS * CONV_DIM * 2;       // bf16 (y in-place)
constexpr size_t OFF_A    = OFF_Z   + ROWS * VAL_DIM * 2;        // f32
constexpr size_t OFF_B    = OFF_A   + ROWS * HV * 4;
constexpr size_t OFF_G    = OFF_B   + ROWS * HV * 4;             // g (log-space)
constexpr size_t OFF_BETA = OFF_G   + ROWS * HV * 4;
constexpr size_t OFF_U    = OFF_BETA + ROWS * HV * 4;            // f32 U (then O)
constexpr size_t OFF_WQK  = OFF_U + (size_t)NCH_TOT * CHUNK * DV * 4;  // bf16 Wqk
constexpr size_t OFF_HALO = OFF_WQK + (size_t)NCH_TOT * CHUNK * CHUNK * 2; // conv halos
constexpr size_t WS_NEED_BYTES = OFF_HALO + (size_t)3 * B * CONV_LT * CONV_DIM * 2;
// overlays (lifetime-disjoint):
constexpr size_t OFF_WCAT = OFF_U;    // Wcat bf16 (NPAD x DIM) until inproj done
constexpr size_t OFF_XB   = OFF_WQK;  // x bf16 until inproj done
constexpr size_t OFF_WOB  = OFF_U;    // Wout bf16 after rmsgate
static_assert((size_t)NPAD * DIM * 2 <= (size_t)NCH_TOT * CHUNK * DV * 4, "Wcat fits U");

// ---------------- bf16 helpers ----------------
__device__ __forceinline__ float bf2f(unsigned short u) {
    union { float f; uint32_t i; } c; c.i = ((uint32_t)u) << 16; return c.f;
}
__device__ __forceinline__ unsigned short f2bf(float f) {
    union { float f; uint32_t u; } c; c.f = f;
    uint32_t u = c.u + 0x7FFFu + ((c.u >> 16) & 1u);   // RTNE
    return (unsigned short)(u >> 16);
}
__device__ __forceinline__ uint32_t pk2(float a, float b) {
    return (uint32_t)f2bf(a) | ((uint32_t)f2bf(b) << 16);
}

// MFMA fragment types (16x16x32 bf16)
typedef __attribute__((ext_vector_type(8))) short bfrag;   // 8 bf16
typedef __attribute__((ext_vector_type(4))) float ffrag;   // 4 f32

// async global->LDS, 16B per lane (dest is wave-uniform base + lane*16)
__device__ __forceinline__ void gload16(const unsigned short* g, unsigned short* l) {
    __builtin_amdgcn_global_load_lds(
        (const __attribute__((address_space(1))) uint32_t*)g,
        (__attribute__((address_space(3))) uint32_t*)l, 16, 0, 0);
}

// ================= f32 -> bf16 conversion kernels =================
__device__ __forceinline__ const float* w_row_multi(int n, const float* Wq, const float* Wz,
                                                    const float* Wa, const float* Wb) {
    if (n < CONV_DIM)                return Wq + (size_t)n * DIM;
    if (n < CONV_DIM + VAL_DIM)      return Wz + (size_t)(n - CONV_DIM) * DIM;
    if (n < CONV_DIM + VAL_DIM + HV) return Wa + (size_t)(n - CONV_DIM - VAL_DIM) * DIM;
    return Wb + (size_t)(n - CONV_DIM - VAL_DIM - HV) * DIM;
}

__global__ __launch_bounds__(256) void cvt_wcat(
    const float* __restrict__ Wq, const float* __restrict__ Wz,
    const float* __restrict__ Wa, const float* __restrict__ Wb,
    unsigned short* __restrict__ dst)
{
    const int r = blockIdx.x;            // 0..NPAD-1
    const int c = threadIdx.x * 8;       // 256*8 = 2048 = DIM
    uint4 o;
    if (r < NPROJ) {
        const float* s = w_row_multi(r, Wq, Wz, Wa, Wb) + c;
        float4 v0 = *(const float4*)s;
        float4 v1 = *(const float4*)(s + 4);
        o = make_uint4(pk2(v0.x, v0.y), pk2(v0.z, v0.w), pk2(v1.x, v1.y), pk2(v1.z, v1.w));
    } else {
        o = make_uint4(0u, 0u, 0u, 0u);
    }
    *(uint4*)&dst[(size_t)r * DIM + c] = o;
}

__global__ __launch_bounds__(256) void cvt_f32bf(const float* __restrict__ src,
                                                 unsigned short* __restrict__ dst, int cols)
{
    const size_t r = blockIdx.x;
    for (int c = threadIdx.x * 8; c < cols; c += 256 * 8) {
        const float* s = src + r * cols + c;
        float4 v0 = *(const float4*)s;
        float4 v1 = *(const float4*)(s + 4);
        *(uint4*)&dst[r * cols + c] =
            make_uint4(pk2(v0.x, v0.y), pk2(v0.z, v0.w), pk2(v1.x, v1.y), pk2(v1.z, v1.w));
    }
}

// ================= shared GEMM epilogue helper (inproj) =================
__device__ __forceinline__ void store_multi(int m, int n, float v,
                                            unsigned short* qkv, unsigned short* z,
                                            float* a, float* b) {
    if (n < CONV_DIM) {
        qkv[(size_t)m * CONV_DIM + n] = f2bf(v);
    } else if (n < CONV_DIM + VAL_DIM) {
        z[(size_t)m * VAL_DIM + (n - CONV_DIM)] = f2bf(v);
    } else if (n < CONV_DIM + VAL_DIM + HV) {
        a[(size_t)m * HV + (n - CONV_DIM - VAL_DIM)] = v;
    } else if (n < NPROJ) {
        b[(size_t)m * HV + (n - CONV_DIM - VAL_DIM - HV)] = v;
    }
}

constexpr int BK = 64;

// ===================================================================
// inproj: 128x128-tile, 2-buffer counted-vmcnt, 64 KiB LDS, 2 blk/CU
// (round-8 measured best: 271 us). T4 + T5.
// ===================================================================
constexpr int GBUF2 = 16384;                 // ushorts per buffer (32 KiB)
constexpr int GEMM_SMEM = 2 * GBUF2 * 2;     // 65536 B

__global__ __launch_bounds__(256) void gemm_inproj_bf(
    const unsigned short* __restrict__ xb,     // (ROWS, DIM)
    const unsigned short* __restrict__ Wcat,   // (NPAD, DIM), pad rows zero
    unsigned short* __restrict__ qkv, unsigned short* __restrict__ z,
    float* __restrict__ a_out, float* __restrict__ b_out)
{
    extern __shared__ __align__(16) unsigned short lds[];

    constexpr int NT  = DIM / BK;              // 32 K-tiles
    constexpr int NBY = (int)ROWS / 128;       // 32
    constexpr int NBX = NPAD / 128;            // 98
    constexpr int NB  = NBY * NBX;             // 3136 (div by 8)
    const int id  = blockIdx.x;
    const int swz = (id & 7) * (NB >> 3) + (id >> 3);
    const int by  = swz & 31;
    const int bx  = swz >> 5;
    const int row0 = by * 128;
    const int col0 = bx * 128;

    const int t = threadIdx.x, lane = t & 63, wid = t >> 6;
    const int wm = (wid >> 1) * 64, wn = (wid & 1) * 64;
    const int quad = lane >> 4, l16 = lane & 15;
    const int x7 = l16 & 7;

    ffrag acc[4][4];
#pragma unroll
    for (int i = 0; i < 4; ++i)
#pragma unroll
        for (int j = 0; j < 4; ++j) acc[i][j] = (ffrag)0.f;

    const int srow = t >> 3;                   // 0..31
    const int scol = (((t & 7) ^ (srow & 7)) * 8);
    const unsigned short* aS = xb   + (size_t)(row0 + srow) * DIM + scol;
    const unsigned short* bS = Wcat + (size_t)(col0 + srow) * DIM + scol;
    unsigned short* aD0 = lds + (wid * 8) * 64;
    unsigned short* bD0 = lds + 8192 + (wid * 8) * 64;

    auto STAGE = [&](int kt) {
        const int b = kt & 1;
        unsigned short* aD = aD0 + b * GBUF2;
        unsigned short* bD = bD0 + b * GBUF2;
        const int k0 = kt * BK;
#pragma unroll
        for (int g = 0; g < 4; ++g) {
            gload16(aS + (size_t)(g * 32) * DIM + k0, aD + g * 32 * 64);
            gload16(bS + (size_t)(g * 32) * DIM + k0, bD + g * 32 * 64);
        }
    };

    auto COMPUTE = [&](int kt) {
        const int b = kt & 1;
        const unsigned short* A  = lds + b * GBUF2;
        const unsigned short* Bm = lds + b * GBUF2 + 8192;
#pragma unroll
        for (int kk = 0; kk < 2; ++kk) {
            const int so = ((kk * 4 + quad) ^ x7) * 8;
            bfrag aF[4], bF[4];
#pragma unroll
            for (int m = 0; m < 4; ++m)
                aF[m] = *(const bfrag*)&A[(wm + m * 16 + l16) * 64 + so];
#pragma unroll
            for (int n = 0; n < 4; ++n)
                bF[n] = *(const bfrag*)&Bm[(wn + n * 16 + l16) * 64 + so];
            __builtin_amdgcn_s_setprio(1);
#pragma unroll
            for (int m = 0; m < 4; ++m)
#pragma unroll
                for (int n = 0; n < 4; ++n)
                    acc[m][n] = __builtin_amdgcn_mfma_f32_16x16x32_bf16(
                        aF[m], bF[n], acc[m][n], 0, 0, 0);
            __builtin_amdgcn_s_setprio(0);
        }
    };

    STAGE(0); STAGE(1);
    asm volatile("s_waitcnt vmcnt(8)" ::: "memory");
    asm volatile("s_barrier" ::: "memory");
    for (int kt = 0; kt < NT; ++kt) {
        COMPUTE(kt);
        if (kt == NT - 1) break;
        asm volatile("s_barrier" ::: "memory");
        if (kt + 2 < NT) {
            STAGE(kt + 2);
            asm volatile("s_waitcnt vmcnt(8)" ::: "memory");
        } else {
            asm volatile("s_waitcnt vmcnt(0)" ::: "memory");
        }
        asm volatile("s_barrier" ::: "memory");
    }

#pragma unroll
    for (int m = 0; m < 4; ++m)
#pragma unroll
        for (int n = 0; n < 4; ++n) {
            int gr = row0 + wm + m * 16 + quad * 4;
            int gc = col0 + wn + n * 16 + l16;
#pragma unroll
            for (int reg = 0; reg < 4; ++reg)
                store_multi(gr + reg, gc, acc[m][n][reg], qkv, z, a_out, b_out);
        }
}

// ===================================================================
// outproj: round-7 measured form — 256x128 tile, 3-deep counted-vmcnt,
// 512 threads / 8 waves, 256 blocks = one CU round.
// ===================================================================
constexpr int GBUF3 = 24576;                 // ushorts per buffer (48 KiB)
constexpr int GEMM3_SMEM = 3 * GBUF3 * 2;    // 147456 B

__global__ __launch_bounds__(512, 1) void gemm_outproj_bf(
    const unsigned short* __restrict__ A,    // (ROWS, VAL_DIM)
    const unsigned short* __restrict__ Wb,   // (DIM, VAL_DIM)
    float* __restrict__ C)                   // (ROWS, DIM)
{
    extern __shared__ __align__(16) unsigned short lds[];

    constexpr int NT  = VAL_DIM / BK;          // 64 K-tiles
    constexpr int NBY = (int)ROWS / 256;       // 16
    constexpr int NBX = DIM / 128;             // 16
    constexpr int NB  = NBY * NBX;             // 256
    const int id  = blockIdx.x;
    const int swz = (id & 7) * (NB >> 3) + (id >> 3);
    const int by  = swz & 15;
    const int bx  = swz >> 4;
    const int row0 = by * 256;
    const int col0 = bx * 128;

    const int t = threadIdx.x, lane = t & 63, wid = t >> 6;
    const int wr = wid >> 1, wc = wid & 1;
    const int quad = lane >> 4, l16 = lane & 15;
    const int x7 = l16 & 7;

    ffrag acc[4][4];
#pragma unroll
    for (int i = 0; i < 4; ++i)
#pragma unroll
        for (int j = 0; j < 4; ++j) acc[i][j] = (ffrag)0.f;

    const int srow = t >> 3;
    const int scol = (((t & 7) ^ (srow & 7)) * 8);
    const unsigned short* aS = A  + (size_t)(row0 + srow) * VAL_DIM + scol;
    const unsigned short* bS = Wb + (size_t)(col0 + srow) * VAL_DIM + scol;
    unsigned short* aD0 = lds + (wid * 8) * 64;
    unsigned short* bD0 = lds + 16384 + (wid * 8) * 64;

    auto STAGE = [&](int kt) {
        const int b = kt % 3;
        unsigned short* aD = aD0 + b * GBUF3;
        unsigned short* bD = bD0 + b * GBUF3;
        const int k0 = kt * BK;
#pragma unroll
        for (int g = 0; g < 4; ++g)
            gload16(aS + (size_t)(g * 64) * VAL_DIM + k0, aD + g * 64 * 64);
#pragma unroll
        for (int g = 0; g < 2; ++g)
            gload16(bS + (size_t)(g * 64) * VAL_DIM + k0, bD + g * 64 * 64);
    };

    auto COMPUTE = [&](int kt) {
        const int b = kt % 3;
        const unsigned short* Am = lds + b * GBUF3;
        const unsigned short* Bm = lds + b * GBUF3 + 16384;
#pragma unroll
        for (int kk = 0; kk < 2; ++kk) {
            const int so = ((kk * 4 + quad) ^ x7) * 8;
            bfrag aF[4], bF[4];
#pragma unroll
            for (int m = 0; m < 4; ++m)
                aF[m] = *(const bfrag*)&Am[(wr * 64 + m * 16 + l16) * 64 + so];
#pragma unroll
            for (int n = 0; n < 4; ++n)
                bF[n] = *(const bfrag*)&Bm[(wc * 64 + n * 16 + l16) * 64 + so];
#pragma unroll
            for (int m = 0; m < 4; ++m)
#pragma unroll
                for (int n = 0; n < 4; ++n)
                    acc[m][n] = __builtin_amdgcn_mfma_f32_16x16x32_bf16(
                        aF[m], bF[n], acc[m][n], 0, 0, 0);
        }
    };

    STAGE(0); STAGE(1);
    asm volatile("s_waitcnt vmcnt(6)" ::: "memory");
    asm volatile("s_barrier" ::: "memory");
    for (int kt = 0; kt < NT; ++kt) {
        if (kt + 2 < NT) {
            STAGE(kt + 2);
            asm volatile("s_waitcnt vmcnt(12)" ::: "memory");
        } else if (kt + 1 < NT) {
            asm volatile("s_waitcnt vmcnt(6)" ::: "memory");
        } else {
            asm volatile("s_waitcnt vmcnt(0)" ::: "memory");
        }
        asm volatile("s_barrier" ::: "memory");
        COMPUTE(kt);
        asm volatile("s_barrier" ::: "memory");
    }

#pragma unroll
    for (int m = 0; m < 4; ++m)
#pragma unroll
        for (int n = 0; n < 4; ++n) {
            int gr = row0 + wr * 64 + m * 16 + quad * 4;
            int gc = col0 + wc * 64 + n * 16 + l16;
#pragma unroll
            for (int reg = 0; reg < 4; ++reg)
                C[(size_t)(gr + reg) * DIM + gc] = acc[m][n][reg];
        }
}

// ================= conv halo snapshot (race-free tiling) =================
__global__ __launch_bounds__(256) void conv_halo(const unsigned short* __restrict__ qkv,
                                                 unsigned short* __restrict__ hbuf)
{
    int idx = blockIdx.x * 256 + threadIdx.x;     // B * CONV_LT * CONV_DIM
    int c    = idx & (CONV_DIM - 1);
    int tile = (idx >> 13) & (CONV_LT - 1);
    int b    = idx >> 16;
    int l0 = tile * CONV_TL;
    const unsigned short* p = qkv + (size_t)b * L * CONV_DIM + c;
#pragma unroll
    for (int j = 0; j < 3; ++j) {
        unsigned short v = (tile > 0) ? p[(size_t)(l0 - 3 + j) * CONV_DIM] : (unsigned short)0;
        hbuf[((size_t)j * B * CONV_LT + b * CONV_LT + tile) * CONV_DIM + c] = v;
    }
}

// ================= depthwise causal conv1d + SiLU (L-tiled) =================
__global__ __launch_bounds__(256) void conv_silu(unsigned short* __restrict__ qkv,
                                                 const float* __restrict__ conv_w,
                                                 const unsigned short* __restrict__ hbuf)
{
    int idx = blockIdx.x * 256 + threadIdx.x;     // B * CONV_LT * CONV_DIM
    int c    = idx & (CONV_DIM - 1);
    int tile = (idx >> 13) & (CONV_LT - 1);
    int b    = idx >> 16;
    const float w0 = conv_w[c * 4 + 0];
    const float w1 = conv_w[c * 4 + 1];
    const float w2 = conv_w[c * 4 + 2];
    const float w3 = conv_w[c * 4 + 3];
    unsigned short* p = qkv + ((size_t)b * L + tile * CONV_TL) * CONV_DIM + c;
    const size_t hb = (size_t)b * CONV_LT + tile;
    float x0 = bf2f(hbuf[((size_t)0 * B * CONV_LT + hb) * CONV_DIM + c]);
    float x1 = bf2f(hbuf[((size_t)1 * B * CONV_LT + hb) * CONV_DIM + c]);
    float x2 = bf2f(hbuf[((size_t)2 * B * CONV_LT + hb) * CONV_DIM + c]);
    for (int l0 = 0; l0 < CONV_TL; l0 += 8) {
        float xv[8];
#pragma unroll
        for (int j = 0; j < 8; ++j) xv[j] = bf2f(p[(size_t)(l0 + j) * CONV_DIM]);
#pragma unroll
        for (int j = 0; j < 8; ++j) {
            float h = w0 * x0 + w1 * x1 + w2 * x2 + w3 * xv[j];
            float s = h / (1.f + __expf(-h));
            p[(size_t)(l0 + j) * CONV_DIM] = f2bf(s);
            x0 = x1; x1 = x2; x2 = xv[j];
        }
    }
}

// ================= l2norm of q,k heads =================
__global__ __launch_bounds__(256) void normqk(unsigned short* __restrict__ qkv)
{
    int wid  = blockIdx.x * 4 + (threadIdx.x >> 6);
    int lane = threadIdx.x & 63;
    int hk  = wid & 15;
    int sel = (wid >> 4) & 1;
    int row = wid >> 5;
    unsigned short* p = qkv + (size_t)row * CONV_DIM + sel * KEY_DIM + hk * DK;
    float x0 = bf2f(p[lane]), x1 = bf2f(p[lane + 64]);
    float ss = x0 * x0 + x1 * x1;
#pragma unroll
    for (int o = 32; o >= 1; o >>= 1) ss += __shfl_xor(ss, o);
    float sc = rsqrtf(ss + 1e-6f);
    if (sel == 0) sc *= 0.08838834764831845f;   // DK^-0.5
    p[lane]      = f2bf(x0 * sc);
    p[lane + 64] = f2bf(x1 * sc);
}

// ================= gate coefficients: g (log) and beta =================
__global__ __launch_bounds__(256) void gatecoef(const float* __restrict__ a_buf,
                                                const float* __restrict__ b_buf,
                                                const float* __restrict__ A_log,
                                                const float* __restrict__ dt_bias,
                                                float* __restrict__ glog,
                                                float* __restrict__ beta)
{
    int idx = blockIdx.x * blockDim.x + threadIdx.x;
    int h = idx & (HV - 1);
    float av = a_buf[idx];
    float bv = b_buf[idx];
    float x  = av + dt_bias[h];
    float sp = (x > 20.f) ? x : log1pf(__expf(x));
    glog[idx] = -__expf(A_log[h]) * sp;
    beta[idx] = 1.f / (1.f + __expf(-bv));
}

// ===================================================================
// Two-pass chunked gated delta rule; pass 1 unchanged.
// ===================================================================

// shared strides
constexpr int RSK  = 136;   // 128-wide bf16 rows (128 data + 8 pad)
constexpr int RST  = 72;    // 64-wide bf16 rows (64 data + 8 pad)
constexpr int RSTD = 68;    // pass-1 X^T rows (64 data + 4 pad)
constexpr int RSR1 = 260;   // pass-1 RHS f32 rows (256 data + 4 pad)

// ---- pass-1 LDS layout ----
constexpr int P1_oKs  = 0;                       // 64*136*2 = 17408
constexpr int P1_oQs  = P1_oKs + 64 * RSK * 2;   // 17408
constexpr int P1_oDT  = 0;                       // overlay Ks+Qs
constexpr int P1_oAf  = P1_oQs + 64 * RSK * 2;   // 34816
constexpr int P1_oRHS = P1_oAf + 64 * RST * 2;   // 44032
constexpr int P1_oG   = P1_oRHS + 64 * RSR1 * 4; // 110592
constexpr int P1_oEG  = P1_oG + 256;
constexpr int P1_oBs  = P1_oEG + 256;
constexpr int P1_SMEM = P1_oBs + 256;            // 111616

__global__ __launch_bounds__(256, 1) void chunk_prep(
    unsigned short* __restrict__ qkv,     // v-slot overwritten with Wkn
    const float* __restrict__ glog,
    const float* __restrict__ beta,
    float* __restrict__ Ubuf,
    unsigned short* __restrict__ Wqkbuf)
{
    extern __shared__ __align__(16) char smem[];
    unsigned short* sKs = (unsigned short*)(smem + P1_oKs);
    unsigned short* sQs = (unsigned short*)(smem + P1_oQs);
    unsigned short* sDT = (unsigned short*)(smem + P1_oDT);
    unsigned short* sAf = (unsigned short*)(smem + P1_oAf);
    float* sRHS = (float*)(smem + P1_oRHS);
    float* sG   = (float*)(smem + P1_oG);
    float* sEG  = (float*)(smem + P1_oEG);
    float* sBs  = (float*)(smem + P1_oBs);

    const int bid = blockIdx.x;
    const int ch = bid & (NCHUNK - 1);
    const int h  = (bid >> 5) & (HV - 1);
    const int bb = bid >> 10;
    const int hk = h >> 1;
    const int t    = threadIdx.x;
    const int w    = t >> 6;
    const int lane = t & 63;
    const int quad = lane >> 4;
    const int l16  = lane & 15;
    const int quad8 = quad * 8;
    const size_t bL = (size_t)bb * L;
    const int l0 = ch * CHUNK;
    const int VOFF = 2 * KEY_DIM + h * DV;

    // ---- loads ----
    {
        const int r  = t >> 2;
        const int c0 = (t & 3) * 32;
        const unsigned short* grow = qkv + (bL + l0 + r) * CONV_DIM;
        const unsigned short* gq = grow + hk * DK + c0;
        const unsigned short* gk = grow + KEY_DIM + hk * DK + c0;
#pragma unroll
        for (int u = 0; u < 4; ++u) {
            *(uint4*)&sKs[r * RSK + c0 + 8 * u] = *(const uint4*)(gk + 8 * u);
            *(uint4*)&sQs[r * RSK + c0 + 8 * u] = *(const uint4*)(gq + 8 * u);
        }
        if (t < 64) {
            float gl = glog[(bL + l0 + t) * HV + h];
#pragma unroll
            for (int off = 1; off < 64; off <<= 1) {
                float v = __shfl_up(gl, off, 64);
                if (lane >= off) gl += v;
            }
            sG[t]  = gl;
            sEG[t] = __expf(gl);
            sBs[t] = beta[(bL + l0 + t) * HV + h];
        }
    }
    __syncthreads();

    // ---- A = K K^T, Wqk = Q K^T ----
    {
        ffrag accA[4], accW[4];
#pragma unroll
        for (int mt = 0; mt < 4; ++mt) { accA[mt] = (ffrag)0.f; accW[mt] = (ffrag)0.f; }
#pragma unroll
        for (int kk = 0; kk < 4; ++kk) {
            bfrag bf = *(const bfrag*)&sKs[(16 * w + l16) * RSK + 32 * kk + quad8];
#pragma unroll
            for (int mt = 0; mt < 4; ++mt) {
                bfrag ak = *(const bfrag*)&sKs[(16 * mt + l16) * RSK + 32 * kk + quad8];
                bfrag aq = *(const bfrag*)&sQs[(16 * mt + l16) * RSK + 32 * kk + quad8];
                accA[mt] = __builtin_amdgcn_mfma_f32_16x16x32_bf16(ak, bf, accA[mt], 0, 0, 0);
                accW[mt] = __builtin_amdgcn_mfma_f32_16x16x32_bf16(aq, bf, accW[mt], 0, 0, 0);
            }
        }
        const int j = 16 * w + l16;
        const float gj = sG[j];
        unsigned short* Wqp = Wqkbuf + (size_t)bid * (CHUNK * CHUNK);
#pragma unroll
        for (int mt = 0; mt < 4; ++mt)
#pragma unroll
            for (int reg = 0; reg < 4; ++reg) {
                int i = 16 * mt + quad * 4 + reg;
                float sc = __expf(sG[i] - gj);
                sAf[i * RST + j] = f2bf((j < i) ? sBs[i] * sc * accA[mt][reg] : 0.f);
                Wqp[i * CHUNK + j] = f2bf((j <= i) ? sc * accW[mt][reg] : 0.f);
            }
    }

    // ---- RHS = [ B*V | B*eG*K ] (f32) ----
    {
        const int r  = t >> 2;
        const int c0 = (t & 3) * 32;
        const float be  = sBs[r];
        const float beg = be * sEG[r];
        const unsigned short* gv = qkv + (bL + l0 + r) * CONV_DIM + VOFF + c0;
#pragma unroll
        for (int u = 0; u < 4; ++u) {
            uint4 vv = *(const uint4*)(gv + 8 * u);
            const unsigned short* vp = (const unsigned short*)&vv;
#pragma unroll
            for (int e = 0; e < 8; ++e)
                sRHS[r * RSR1 + c0 + 8 * u + e] = be * bf2f(vp[e]);
        }
#pragma unroll
        for (int u = 0; u < 4; ++u)
#pragma unroll
            for (int e = 0; e < 8; ++e)
                sRHS[r * RSR1 + 128 + c0 + 8 * u + e] =
                    beg * bf2f(sKs[r * RSK + c0 + 8 * u + e]);
    }
    __syncthreads();   // Ks/Qs reads done -> DT overlay writable

    for (int u = t; u < 256 * RSTD / 2; u += 256) ((uint32_t*)sDT)[u] = 0;

    // ---- blocked forward substitution, 256 columns ----
    float* Up = Ubuf + (size_t)bid * (CHUNK * DV);
    for (int sb = 0; sb < 4; ++sb) {
        const int sb16 = 16 * sb;
        if (sb > 0) {
            const int kbn = (sb + 1) >> 1;
            ffrag c16[4];
#pragma unroll
            for (int nt = 0; nt < 4; ++nt) c16[nt] = (ffrag)0.f;
            for (int kb = 0; kb < kbn; ++kb) {
                bfrag af = *(const bfrag*)&sAf[(sb16 + l16) * RST + 32 * kb + quad8];
#pragma unroll
                for (int nt = 0; nt < 4; ++nt) {
                    bfrag bf = *(const bfrag*)&sDT[(64 * w + 16 * nt + l16) * RSTD + 32 * kb + quad8];
                    c16[nt] = __builtin_amdgcn_mfma_f32_16x16x32_bf16(af, bf, c16[nt], 0, 0, 0);
                }
            }
#pragma unroll
            for (int nt = 0; nt < 4; ++nt)
#pragma unroll
                for (int reg = 0; reg < 4; ++reg)
                    sRHS[(sb16 + quad * 4 + reg) * RSR1 + 64 * w + 16 * nt + l16] -= c16[nt][reg];
        }
        __syncthreads();
        {   // serial 16x16 unit-lower solve; thread t owns column t
            const int c = t;
            float d16[16];
#pragma unroll
            for (int e = 0; e < 16; ++e) {
                const int i = sb16 + e;
                float acc = sRHS[i * RSR1 + c];
#pragma unroll
                for (int f = 0; f < 16; ++f)
                    if (f < e) acc -= bf2f(sAf[i * RST + sb16 + f]) * d16[f];
                d16[e] = acc;
            }
#pragma unroll
            for (int e = 0; e < 16; e += 2)
                *(uint32_t*)&sDT[c * RSTD + sb16 + e] = pk2(d16[e], d16[e + 1]);
            if (c < 128) {
                float* up = Up + c;
#pragma unroll
                for (int e = 0; e < 16; ++e) up[(size_t)(sb16 + e) * DV] = d16[e];
            } else {
                unsigned short* wp = qkv + (bL + l0 + sb16) * CONV_DIM + VOFF + (c - 128);
#pragma unroll
                for (int e = 0; e < 16; ++e) wp[(size_t)e * CONV_DIM] = f2bf(-d16[e]);
            }
        }
        __syncthreads();
    }
}

// ===================================================================
// Pass 2 (chunk_scan3): dv-split scan. The recurrence is independent
// per dv channel: Delta[i][dv], O[i][dv], ST[dv][:] only couple via dv.
// Grid = (b,h,g) = 256 blocks (g = dv-group of 32), 4 waves each.
// O written f32 over the consumed U slice (per-block-disjoint columns).
// RMSNorm + silu(z) gate moved to rmsgate kernel (cross-dv coupling).
// ===================================================================
constexpr int S3_oKT  = 0;                        // 128*72*2 = 18432
constexpr int S3_oQs  = S3_oKT + 128 * RST * 2;   // +17408
constexpr int S3_oWk  = S3_oQs + 64 * RSK * 2;    // +17408
constexpr int S3_oWqk = S3_oWk + 64 * RSK * 2;    // +9216
constexpr int S3_oSTb = S3_oWqk + 64 * RST * 2;   // +8704 (32*136*2)
constexpr int S3_oDT  = S3_oSTb + 32 * RSK * 2;   // +4608 (32*72*2)
constexpr int S3_oDdT = S3_oDT + 32 * RST * 2;    // +4608
constexpr int S3_oEG  = S3_oDdT + 32 * RST * 2;   // 80384
constexpr int S3_oEGd = S3_oEG + 256;             // 80640
constexpr int S3_SMEM = S3_oEGd + 256;            // 80896

__global__ __launch_bounds__(256, 1) void chunk_scan3(
    const unsigned short* __restrict__ qkv,   // q,k raw; v-slot holds Wkn
    const float* __restrict__ glog,
    float* __restrict__ Ubuf,                 // U in, O out (f32, in place)
    const unsigned short* __restrict__ Wqkbuf)
{
    extern __shared__ __align__(16) char smem[];
    unsigned short* sKT  = (unsigned short*)(smem + S3_oKT);
    unsigned short* sQs  = (unsigned short*)(smem + S3_oQs);
    unsigned short* sWk  = (unsigned short*)(smem + S3_oWk);
    unsigned short* sWqk = (unsigned short*)(smem + S3_oWqk);
    unsigned short* sSTb = (unsigned short*)(smem + S3_oSTb);
    unsigned short* sDT  = (unsigned short*)(smem + S3_oDT);
    unsigned short* sDdT = (unsigned short*)(smem + S3_oDdT);
    float* sEG  = (float*)(smem + S3_oEG);
    float* sEGd = (float*)(smem + S3_oEGd);

    const int g  = blockIdx.x & 3;           // dv group
    const int bh = blockIdx.x >> 2;
    const int h  = bh & (HV - 1);
    const int bb = bh >> 5;
    const int hk = h >> 1;
    const int DV0 = g * 32;
    const int t    = threadIdx.x;            // 0..255
    const int w    = t >> 6;                 // 0..3 (row-tile of i)
    const int lane = t & 63;
    const int quad = lane >> 4;
    const int l16  = lane & 15;
    const int quad8 = quad * 8;
    const size_t bL = (size_t)bb * L;
    const int VOFF = 2 * KEY_DIM + h * DV;
    const size_t chbase0 = ((size_t)bb * HV + h) * NCHUNK;

    const int r  = t >> 2;        // staging row 0..63
    const int c0 = (t & 3) * 32;  // staging col
    const int cw = (t & 3) * 16;  // Wqk col

    // persistent state slice: ST[dv 32][dk 128]; wave w owns dk [32w,32w+32)
    ffrag accS[2][2];
#pragma unroll
    for (int m = 0; m < 2; ++m)
#pragma unroll
        for (int n = 0; n < 2; ++n) accS[m][n] = (ffrag)0.f;

    for (int u = t; u < 32 * RSK / 2; u += 256) ((uint32_t*)sSTb)[u] = 0;

    // prefetch registers (issue-early / write-late)
    uint4 pQ[4], pK[4], pWk[4], pWqk2[2];
    float pGl;

    auto PF = [&](int ch) {
        const int l0p = ch * CHUNK;
        const unsigned short* grow = qkv + (bL + l0p + r) * CONV_DIM;
        const unsigned short* gq = grow + hk * DK + c0;
        const unsigned short* gk = grow + KEY_DIM + hk * DK + c0;
        const unsigned short* gw = grow + VOFF + c0;
#pragma unroll
        for (int u = 0; u < 4; ++u) {
            pQ[u]  = *(const uint4*)(gq + 8 * u);
            pK[u]  = *(const uint4*)(gk + 8 * u);
            pWk[u] = *(const uint4*)(gw + 8 * u);
        }
        const unsigned short* qp = Wqkbuf + (chbase0 + ch) * (CHUNK * CHUNK) + r * CHUNK + cw;
        pWqk2[0] = *(const uint4*)qp;
        pWqk2[1] = *(const uint4*)(qp + 8);
        pGl = glog[(bL + l0p + (t & 63)) * HV + h];
    };

    PF(0);

    for (int ch = 0; ch < NCHUNK; ++ch) {
        const size_t cb = chbase0 + ch;
        float* Uch = Ubuf + cb * (CHUNK * DV);
        __syncthreads();   // A: prev STb written; all prev LDS reads done

        // ---- U -> accD direct from global (rows i in [16w,16w+16)) ----
        ffrag accD[2];
        {
            const float* up = Uch + (size_t)(16 * w + quad * 4) * DV + DV0 + l16;
#pragma unroll
            for (int nt = 0; nt < 2; ++nt)
#pragma unroll
                for (int reg = 0; reg < 4; ++reg)
                    accD[nt][reg] = up[(size_t)reg * DV + 16 * nt];
        }

        // ---- stage LDS from prefetch regs ----
#pragma unroll
        for (int u = 0; u < 4; ++u) {
            *(uint4*)&sQs[r * RSK + c0 + 8 * u] = pQ[u];
            *(uint4*)&sWk[r * RSK + c0 + 8 * u] = pWk[u];
            const unsigned short* kp = (const unsigned short*)&pK[u];
#pragma unroll
            for (int e = 0; e < 8; ++e) {
                const int c = c0 + 8 * u + e;
                sKT[c * RST + ((((r >> 3) ^ (c >> 3)) & 7) << 3) + (r & 7)] = kp[e];
            }
        }
        *(uint4*)&sWqk[r * RST + cw]     = pWqk2[0];
        *(uint4*)&sWqk[r * RST + cw + 8] = pWqk2[1];

        // gates (cumulative log-decay scan, wave 0 only)
        {
            float gl = pGl;
            if (t < 64) {
#pragma unroll
                for (int off = 1; off < 64; off <<= 1) {
                    float v = __shfl_up(gl, off, 64);
                    if (lane >= off) gl += v;
                }
                float gc = __shfl(gl, 63, 64);
                sEG[t]  = __expf(gl);
                sEGd[t] = __expf(gc - gl);
            }
        }

        if (ch + 1 < NCHUNK) PF(ch + 1);   // next-chunk loads fly across compute
        __syncthreads();   // B

        // ---- Delta(64x32) = U + Wkn . ST  (wave w: rows [16w,16w+16)) ----
#pragma unroll
        for (int kk = 0; kk < 4; ++kk) {
            bfrag af = *(const bfrag*)&sWk[(16 * w + l16) * RSK + 32 * kk + quad8];
#pragma unroll
            for (int nt = 0; nt < 2; ++nt) {
                bfrag bf = *(const bfrag*)&sSTb[(16 * nt + l16) * RSK + 32 * kk + quad8];
                accD[nt] = __builtin_amdgcn_mfma_f32_16x16x32_bf16(af, bf, accD[nt], 0, 0, 0);
            }
        }

        // ---- packed Delta^T / decayed Delta^T writes ([dv 32][i 64]) ----
        {
            const int i0 = 16 * w + quad * 4;
            const float e0 = sEGd[i0], e1 = sEGd[i0 + 1], e2 = sEGd[i0 + 2], e3 = sEGd[i0 + 3];
#pragma unroll
            for (int nt = 0; nt < 2; ++nt) {
                const int dv = 16 * nt + l16;
                const float d0 = accD[nt][0], d1 = accD[nt][1];
                const float d2 = accD[nt][2], d3 = accD[nt][3];
                *(uint32_t*)&sDT[dv * RST + i0]      = pk2(d0, d1);
                *(uint32_t*)&sDT[dv * RST + i0 + 2]  = pk2(d2, d3);
                *(uint32_t*)&sDdT[dv * RST + i0]     = pk2(d0 * e0, d1 * e1);
                *(uint32_t*)&sDdT[dv * RST + i0 + 2] = pk2(d2 * e2, d3 * e3);
            }
        }
        __syncthreads();   // D

        // ---- O(64x32) = eG*(Q ST) + Wqk . Delta  (rows [16w,16w+16)) ----
        ffrag accO[2];
#pragma unroll
        for (int nt = 0; nt < 2; ++nt) accO[nt] = (ffrag)0.f;
#pragma unroll
        for (int kk = 0; kk < 4; ++kk) {
            bfrag af = *(const bfrag*)&sQs[(16 * w + l16) * RSK + 32 * kk + quad8];
#pragma unroll
            for (int nt = 0; nt < 2; ++nt) {
                bfrag bf = *(const bfrag*)&sSTb[(16 * nt + l16) * RSK + 32 * kk + quad8];
                accO[nt] = __builtin_amdgcn_mfma_f32_16x16x32_bf16(af, bf, accO[nt], 0, 0, 0);
            }
        }
#pragma unroll
        for (int nt = 0; nt < 2; ++nt)
#pragma unroll
            for (int reg = 0; reg < 4; ++reg)
                accO[nt][reg] *= sEG[16 * w + quad * 4 + reg];
#pragma unroll
        for (int kk = 0; kk < 2; ++kk) {
            bfrag af = *(const bfrag*)&sWqk[(16 * w + l16) * RST + 32 * kk + quad8];
#pragma unroll
            for (int nt = 0; nt < 2; ++nt) {
                bfrag bf = *(const bfrag*)&sDT[(16 * nt + l16) * RST + 32 * kk + quad8];
                accO[nt] = __builtin_amdgcn_mfma_f32_16x16x32_bf16(af, bf, accO[nt], 0, 0, 0);
            }
        }
        // write O (f32) over the consumed U slice (block-disjoint columns)
        {
            float* op = Uch + (size_t)(16 * w + quad * 4) * DV + DV0 + l16;
#pragma unroll
            for (int nt = 0; nt < 2; ++nt)
#pragma unroll
                for (int reg = 0; reg < 4; ++reg)
                    op[(size_t)reg * DV + 16 * nt] = accO[nt][reg];
        }

        // ---- state: ST[dv][dk] = eGc*ST + DdT . KT (wave w: dk [32w,32w+32)) ----
        {
            const float eGc = sEG[63];
#pragma unroll
            for (int m = 0; m < 2; ++m)
#pragma unroll
                for (int n = 0; n < 2; ++n)
#pragma unroll
                    for (int reg = 0; reg < 4; ++reg) accS[m][n][reg] *= eGc;
#pragma unroll
            for (int kk = 0; kk < 2; ++kk) {
#pragma unroll
                for (int m = 0; m < 2; ++m) {
                    bfrag a0 = *(const bfrag*)&sDdT[(16 * m + l16) * RST + 32 * kk + quad8];
#pragma unroll
                    for (int n = 0; n < 2; ++n) {
                        const int ck = 32 * w + 16 * n + l16;
                        bfrag bk = *(const bfrag*)&sKT[ck * RST +
                                     ((((4 * kk + quad) ^ (ck >> 3)) & 7) << 3)];
                        accS[m][n] = __builtin_amdgcn_mfma_f32_16x16x32_bf16(a0, bk, accS[m][n], 0, 0, 0);
                    }
                }
            }
        }
        __syncthreads();   // E: all STb/DT/DdT/KT reads done

        // ---- materialize STb (bf16) for next chunk (own dk cols) ----
#pragma unroll
        for (int m = 0; m < 2; ++m)
#pragma unroll
            for (int n = 0; n < 2; ++n)
#pragma unroll
                for (int reg = 0; reg < 4; ++reg)
                    sSTb[(16 * m + quad * 4 + reg) * RSK + 32 * w + 16 * n + l16] =
                        f2bf(accS[m][n][reg]);
    }
}

// ================= RMSNorm + silu(z) gate epilogue =================
// One wave per (row, h): O (f32, in Ubuf layout) -> y (bf16, over z).
__global__ __launch_bounds__(256) void rmsgate(
    const float* __restrict__ Obuf,
    unsigned short* __restrict__ z_io,
    const float* __restrict__ norm_w)
{
    const int gw   = blockIdx.x * 4 + (threadIdx.x >> 6);
    const int lane = threadIdx.x & 63;
    const int h  = gw & (HV - 1);
    const int lg = gw >> 5;                  // 0..4095 global row
    const int bb = lg >> 11;
    const int l  = lg & (L - 1);
    const int ch = l >> 6, i = l & 63;
    const size_t cb = ((size_t)bb * HV + h) * NCHUNK + ch;
    const int dv0 = lane * 2;

    float2 o = *(const float2*)(Obuf + cb * (CHUNK * DV) + (size_t)i * DV + dv0);
    float p = o.x * o.x + o.y * o.y;
#pragma unroll
    for (int m = 1; m < 64; m <<= 1) p += __shfl_xor(p, m, 64);
    float inv = rsqrtf(p * (1.f / 128.f) + EPS);

    unsigned short* zp = z_io + ((size_t)bb * L + l) * VAL_DIM + h * DV + dv0;
    uint32_t zu = *(const uint32_t*)zp;
    float z0 = bf2f((unsigned short)(zu & 0xFFFF));
    float z1 = bf2f((unsigned short)(zu >> 16));
    float y0 = o.x * inv * norm_w[dv0]     * (z0 / (1.f + __expf(-z0)));
    float y1 = o.y * inv * norm_w[dv0 + 1] * (z1 / (1.f + __expf(-z1)));
    *(uint32_t*)zp = pk2(y0, y1);
}

// ---------------- launch ----------------
extern "C" void kernel_launch(void* const* d_in, const int* in_sizes, int n_in,
                              void* d_out, int out_size, void* d_ws, size_t ws_size,
                              hipStream_t stream)
{
    const float* x        = (const float*)d_in[0];
    const float* W_qkv    = (const float*)d_in[1];
    const float* W_z      = (const float*)d_in[2];
    const float* W_a      = (const float*)d_in[3];
    const float* W_b      = (const float*)d_in[4];
    const float* conv_w   = (const float*)d_in[5];
    const float* A_log    = (const float*)d_in[6];
    const float* dt_bias  = (const float*)d_in[7];
    const float* norm_w   = (const float*)d_in[8];
    const float* W_out    = (const float*)d_in[9];
    float* out = (float*)d_out;
    char*  ws  = (char*)d_ws;

    if (ws_size < WS_NEED_BYTES) return;

    unsigned short* qkv = (unsigned short*)(ws + OFF_QKV);
    unsigned short* z   = (unsigned short*)(ws + OFF_Z);
    float* a    = (float*)(ws + OFF_A);
    float* bbuf = (float*)(ws + OFF_B);
    float* gl   = (float*)(ws + OFF_G);
    float* beta = (float*)(ws + OFF_BETA);
    float* Ubuf = (float*)(ws + OFF_U);
    unsigned short* Wqkbuf = (unsigned short*)(ws + OFF_WQK);
    unsigned short* hbuf   = (unsigned short*)(ws + OFF_HALO);
    unsigned short* Wcat   = (unsigned short*)(ws + OFF_WCAT);  // overlay on U
    unsigned short* xb     = (unsigned short*)(ws + OFF_XB);    // overlay on Wqk
    unsigned short* Wob    = (unsigned short*)(ws + OFF_WOB);   // overlay on U

    static bool attr_set = false;
    if (!attr_set) {
        (void)hipFuncSetAttribute((const void*)chunk_prep,
                                  hipFuncAttributeMaxDynamicSharedMemorySize, P1_SMEM);
        (void)hipFuncSetAttribute((const void*)chunk_scan3,
                                  hipFuncAttributeMaxDynamicSharedMemorySize, S3_SMEM);
        (void)hipFuncSetAttribute((const void*)gemm_inproj_bf,
                                  hipFuncAttributeMaxDynamicSharedMemorySize, GEMM_SMEM);
        (void)hipFuncSetAttribute((const void*)gemm_outproj_bf,
                                  hipFuncAttributeMaxDynamicSharedMemorySize, GEMM3_SMEM);
        attr_set = true;
    }

    // 0. pre-convert operands to bf16
    cvt_wcat<<<NPAD, 256, 0, stream>>>(W_qkv, W_z, W_a, W_b, Wcat);
    cvt_f32bf<<<(int)ROWS, 256, 0, stream>>>(x, xb, DIM);
    // 1. fused input projections (128^2 tile, 2-buf counted-vmcnt, 2 blocks/CU)
    gemm_inproj_bf<<<((int)ROWS / 128) * (NPAD / 128), 256, GEMM_SMEM, stream>>>(
        xb, Wcat, qkv, z, a, bbuf);
    // 2. depthwise causal conv + silu (L-tiled, halo snapshot first)
    conv_halo<<<(B * CONV_LT * CONV_DIM) / 256, 256, 0, stream>>>(qkv, hbuf);
    conv_silu<<<(B * CONV_LT * CONV_DIM) / 256, 256, 0, stream>>>(qkv, conv_w, hbuf);
    // 3. l2norm q,k heads
    normqk<<<(B * L * 2 * HK) / 4, 256, 0, stream>>>(qkv);
    // 4. gate coefficients (log-space g)
    gatecoef<<<(B * L * HV) / 256, 256, 0, stream>>>(a, bbuf, A_log, dt_bias, gl, beta);
    // 5a. parallel chunk prep: A, Wqk, solve -> U (f32), Wkn (v-slot)
    chunk_prep<<<NCH_TOT, 256, P1_SMEM, stream>>>(qkv, gl, beta, Ubuf, Wqkbuf);
    // 5b. dv-split sequential scan: 256 blocks, O overwrites U (f32)
    chunk_scan3<<<B * HV * 4, 256, S3_SMEM, stream>>>(qkv, gl, Ubuf, Wqkbuf);
    // 5c. RMSNorm + silu(z) gate epilogue: y overwrites z
    rmsgate<<<(int)(ROWS * HV) / 4, 256, 0, stream>>>(Ubuf, z, norm_w);
    // 5d. convert W_out to bf16 (U dead now; overlay)
    cvt_f32bf<<<DIM, 256, 0, stream>>>(W_out, Wob, VAL_DIM);
    // 6. output projection (256x128 tile, 3-deep pipeline; 256 blocks = 1 round)
    gemm_outproj_bf<<<((int)ROWS / 256) * (DIM / 128), 512, GEMM3_SMEM, stream>>>(z, Wob, out);
}